// Round 11
// baseline (250.021 us; speedup 1.0000x reference)
//
#include <hip/hip_runtime.h>
#include <hip/hip_fp16.h>

typedef unsigned int u32;
typedef unsigned short u16;

#define NIMG 16
#define HH 512
#define WW 512
#define HWSZ (HH*WW)
#define TOPN 2621u
#define TIE_CAP 8192
#define GR 40

// ---------- f16 packing helpers ----------
static __device__ inline u16 f2h(float v){ __half h=__float2half_rn(v); return *reinterpret_cast<u16*>(&h); }
static __device__ inline float h2f(u16 v){ __half h=*reinterpret_cast<__half*>(&v); return __half2float(h); }
static __device__ inline uint2 pack_h4(float4 S){
  __half2 lo = __floats2half2_rn(S.x, S.y);
  __half2 hi = __floats2half2_rn(S.z, S.w);
  uint2 r;
  r.x = *reinterpret_cast<unsigned int*>(&lo);
  r.y = *reinterpret_cast<unsigned int*>(&hi);
  return r;
}
static __device__ inline float4 unpack_h4(uint2 v){
  __half2 lo = *reinterpret_cast<__half2*>(&v.x);
  __half2 hi = *reinterpret_cast<__half2*>(&v.y);
  float2 A = __half22float2(lo), B = __half22float2(hi);
  return make_float4(A.x, A.y, B.x, B.y);
}
static __device__ inline u32 pack_h2(float a, float b){
  __half2 h = __floats2half2_rn(a, b);
  return *reinterpret_cast<unsigned int*>(&h);
}
static __device__ inline float2 unpack_h2(u32 v){
  __half2 h = *reinterpret_cast<__half2*>(&v);
  return __half22float2(h);
}

// ---------------- prep: x -> img16(3 planes), guid16, row-min f32 (dark path), zero state ----------------
__global__ void k_prep(const float* __restrict__ x, u16* __restrict__ imgh,
                       u16* __restrict__ guidh, float* __restrict__ rowm,
                       u32* __restrict__ state, int zwords){
  __shared__ float s[WW+14];
  int row = blockIdx.x; int n = row>>9; int y = row&511; int t = threadIdx.x;
  int zi = row*512 + t;
  if(zi < zwords) state[zi] = 0;
  const float* xb = x + (size_t)n*3*HWSZ + (size_t)y*WW + t;
  float x0=xb[0], x1=xb[HWSZ], x2=xb[2*HWSZ];
  float i0=(x0+1.f)*0.5f, i1=(x1+1.f)*0.5f, i2=(x2+1.f)*0.5f;
  size_t po = (size_t)n*3*HWSZ + (size_t)y*WW + t;
  imgh[po] = f2h(i0); imgh[po+HWSZ] = f2h(i1); imgh[po+2*HWSZ] = f2h(i2);
  float g = (0.2989f*x0 + 0.587f*x1 + 0.114f*x2 + 1.f)*0.5f;   // exact reference form
  size_t qo = (size_t)n*HWSZ + (size_t)y*WW + t;
  guidh[qo] = f2h(g);
  float m = fminf(i0, fminf(i1, i2));
  s[t+7] = m;
  if(t < 7) s[t] = 1.0f;
  if(t >= WW-7) s[t+14] = 1.0f;
  __syncthreads();
  float v = s[t];
  #pragma unroll
  for(int d=1; d<15; ++d) v = fminf(v, s[t+d]);
  rowm[qo] = v;
}

// ---------------- 15-tap col min f32 (dark) + fused hist1 (same-block LDS) ----------------
__global__ void k_colmin_dark(const float* __restrict__ in, float* __restrict__ out,
                              u32* __restrict__ hist1){
  __shared__ u32 h[8192];
  int x4 = threadIdx.x;            // 128 threads = 512 floats
  int y = blockIdx.x;
  int n = blockIdx.y;
  for(int i=x4; i<8192; i+=128) h[i] = 0;
  const float4* base = (const float4*)(in + (size_t)n*HWSZ);
  float4 v = {3.0e38f,3.0e38f,3.0e38f,3.0e38f};
  #pragma unroll
  for(int d=-7; d<=7; ++d){
    int yy = y + d;
    if(yy >= 0 && yy < HH){
      float4 tp = base[(size_t)yy*(WW/4) + x4];
      v.x=fminf(v.x,tp.x); v.y=fminf(v.y,tp.y); v.z=fminf(v.z,tp.z); v.w=fminf(v.w,tp.w);
    } else {
      v.x=fminf(v.x,1.f); v.y=fminf(v.y,1.f); v.z=fminf(v.z,1.f); v.w=fminf(v.w,1.f);
    }
  }
  __syncthreads();   // LDS hist zeroed
  u32 kb[4];
  kb[0]=__float_as_uint(v.x); kb[1]=__float_as_uint(v.y);
  kb[2]=__float_as_uint(v.z); kb[3]=__float_as_uint(v.w);
  #pragma unroll
  for(int k=0; k<4; ++k){
    int b = (int)(kb[k] >> 10) - 0xFC000;
    b = max(0, min(8191, b));
    atomicAdd(&h[b], 1u);
  }
  ((float4*)(out + (size_t)n*HWSZ))[(size_t)y*(WW/4) + x4] = v;
  __syncthreads();
  u32* gh = hist1 + n*8192;
  for(int i=x4; i<8192; i+=128) if(h[i]) atomicAdd(&gh[i], h[i]);
}

__device__ inline u32 block_scan_incl(u32 v, int t, u32* wsum){
  #pragma unroll
  for(int d=1; d<64; d<<=1){
    u32 u = __shfl_up(v, d);
    if((t & 63) >= d) v += u;
  }
  if((t & 63) == 63) wsum[t >> 6] = v;
  __syncthreads();
  u32 carry = 0;
  for(int w=0; w < (t >> 6); ++w) carry += wsum[w];
  return v + carry;
}

// ---------------- hist2 with redundant csel1 prologue (plain loads, no fences) ----------------
__global__ void k_hist2(const float* __restrict__ dark, const u32* __restrict__ hist1,
                        u32* __restrict__ hist2, u32* __restrict__ st){
  __shared__ u32 h[1024];
  __shared__ u32 wsum[16];
  __shared__ u32 bc[2];
  int n = blockIdx.x, part = blockIdx.y, t = threadIdx.x;   // 1024 threads
  h[t] = 0;
  // csel1 prologue: every block redundantly scans hist1 (built in a prior dispatch)
  const u32* hh = hist1 + n*8192;
  u32 loc[8]; u32 ps = 0;
  #pragma unroll
  for(int k=0; k<8; ++k){
    loc[k] = hh[8191 - (t*8 + k)];
    ps += loc[k];
  }
  u32 incl = block_scan_incl(ps, t, wsum);
  u32 excl = incl - ps;
  if(excl < TOPN && incl >= TOPN){
    u32 cum = excl;
    #pragma unroll
    for(int k=0; k<8; ++k){
      if(cum + loc[k] >= TOPN){
        bc[0] = (u32)(8191 - (t*8+k));
        bc[1] = cum;
        st[n*16+0] = bc[0];          // racing identical writes across blocks: benign
        st[n*16+1] = cum;
        break;
      }
      cum += loc[k];
    }
  }
  __syncthreads();
  int bin_hi = (int)bc[0];
  const u32* d = (const u32*)(dark + (size_t)n*HWSZ);
  int per = HWSZ/8, i0 = part*per;
  for(int i=i0+t; i<i0+per; i+=1024){
    u32 key = d[i];
    if(((int)(key >> 10) - 0xFC000) == bin_hi) atomicAdd(&h[key & 1023u], 1u);
  }
  __syncthreads();
  if(h[t]) atomicAdd(&hist2[n*1024 + t], h[t]);
}

// ---------------- sel4 with redundant csel2 prologue; sums over dark > v*, gather ties ----------------
__global__ void k_sel4(const float* __restrict__ dark, const float* __restrict__ x,
                       const u32* __restrict__ hist2, u32* __restrict__ st,
                       float* __restrict__ sums, u32* __restrict__ ties){
  __shared__ u32 wsum[16];
  __shared__ u32 bc[1];
  __shared__ float red[1024];
  int n = blockIdx.x, part = blockIdx.y, t = threadIdx.x;
  // csel2 prologue: every block redundantly scans hist2
  u32 bin_hi    = st[n*16+0];
  u32 cnt_above = st[n*16+1];
  u32 cnt = hist2[n*1024 + (1023 - t)];
  u32 incl = block_scan_incl(cnt, t, wsum);
  u32 excl = incl - cnt;
  u32 need = TOPN - cnt_above;
  if(excl < need && incl >= need){
    u32 lo = (u32)(1023 - t);
    u32 cnt_gt = cnt_above + excl;
    bc[0] = ((bin_hi + 0xFC000u) << 10) | lo;
    st[n*16+6] = TOPN - cnt_gt;     // k_need for sel5 (racing identical writes: benign)
  }
  __syncthreads();
  u32 vb = bc[0];
  const u32* d = (const u32*)(dark + (size_t)n*HWSZ);
  const float* xb = x + (size_t)n*3*HWSZ;
  float a0=0.f, a1=0.f, a2=0.f;
  int per = HWSZ/8, i0 = part*per;
  for(int i=i0+t; i<i0+per; i+=1024){
    u32 key = d[i];
    if(key > vb){
      a0 += xb[i]; a1 += xb[i+HWSZ]; a2 += xb[i+2*HWSZ];
    } else if(key == vb){
      u32 pos = atomicAdd(&st[n*16+7], 1u);
      if(pos < TIE_CAP) ties[n*TIE_CAP + pos] = (u32)i;
    }
  }
  red[t]=a0; __syncthreads();
  for(int s=512;s>0;s>>=1){ if(t<s) red[t]+=red[t+s]; __syncthreads(); }
  if(t==0) atomicAdd(&sums[n*8+0], red[0]);
  __syncthreads();
  red[t]=a1; __syncthreads();
  for(int s=512;s>0;s>>=1){ if(t<s) red[t]+=red[t+s]; __syncthreads(); }
  if(t==0) atomicAdd(&sums[n*8+1], red[0]);
  __syncthreads();
  red[t]=a2; __syncthreads();
  for(int s=512;s>0;s>>=1){ if(t<s) red[t]+=red[t+s]; __syncthreads(); }
  if(t==0) atomicAdd(&sums[n*8+2], red[0]);
}

// ---------------- sel5: exact top_k tie-break by smallest index (binary search cutoff) ----------------
__global__ void k_sel5(const float* __restrict__ x, const u32* __restrict__ st,
                       const float* __restrict__ sums, const u32* __restrict__ ties,
                       float* __restrict__ A){
  __shared__ u32 tl[TIE_CAP];
  __shared__ u32 redu[1024];
  __shared__ float red[1024];
  __shared__ float fin[3];
  int n = blockIdx.x, t = threadIdx.x;   // 1024
  u32 k_need = st[n*16+6];
  u32 m = st[n*16+7]; if(m > TIE_CAP) m = TIE_CAP;
  const float* xb = x + (size_t)n*3*HWSZ;
  const u32* tb = ties + n*TIE_CAP;
  for(u32 e=t; e<m; e+=1024) tl[e] = tb[e];
  __syncthreads();
  u32 lo = 0, hi = HWSZ;
  while(lo < hi){
    u32 mid = (lo + hi) >> 1;
    u32 c = 0;
    for(u32 e=t; e<m; e+=1024) c += (tl[e] < mid) ? 1u : 0u;
    redu[t] = c; __syncthreads();
    for(int s=512;s>0;s>>=1){ if(t<s) redu[t]+=redu[t+s]; __syncthreads(); }
    u32 total = redu[0]; __syncthreads();
    if(total >= k_need) hi = mid; else lo = mid + 1;
  }
  u32 C = lo;
  float a0=0.f, a1=0.f, a2=0.f;
  for(u32 e=t; e<m; e+=1024){
    u32 idx = tl[e];
    if(idx < C){ a0 += xb[idx]; a1 += xb[idx+HWSZ]; a2 += xb[idx+2*HWSZ]; }
  }
  red[t]=a0; __syncthreads();
  for(int s=512;s>0;s>>=1){ if(t<s) red[t]+=red[t+s]; __syncthreads(); }
  if(t==0) fin[0]=red[0];
  __syncthreads();
  red[t]=a1; __syncthreads();
  for(int s=512;s>0;s>>=1){ if(t<s) red[t]+=red[t+s]; __syncthreads(); }
  if(t==0) fin[1]=red[0];
  __syncthreads();
  red[t]=a2; __syncthreads();
  for(int s=512;s>0;s>>=1){ if(t<s) red[t]+=red[t+s]; __syncthreads(); }
  if(t==0){
    fin[2]=red[0];
    for(int c=0;c<3;++c){
      float tot = sums[n*8+c] + fin[c];
      float Ac = (tot / 2621.0f + 1.0f) * 0.5f;
      A[n*8+c]   = Ac;
      A[n*8+4+c] = 1.0f / Ac;
    }
  }
}

// ---------------- rowmin of img/A (f16 img in, f16 out) ----------------
__global__ void k_rowmin2(const u16* __restrict__ imgh, const float* __restrict__ A,
                          u16* __restrict__ rowm2){
  __shared__ float s[WW+14];
  int row = blockIdx.x; int n = row>>9; int y = row&511; int t = threadIdx.x;
  float ia0=A[n*8+4], ia1=A[n*8+5], ia2=A[n*8+6];
  size_t po = (size_t)n*3*HWSZ + (size_t)y*WW + t;
  float i0=h2f(imgh[po]), i1=h2f(imgh[po+HWSZ]), i2=h2f(imgh[po+2*HWSZ]);
  float m = fminf(i0*ia0, fminf(i1*ia1, i2*ia2));
  s[t+7] = m;
  if(t < 7) s[t] = 1.0f;
  if(t >= WW-7) s[t+14] = 1.0f;
  __syncthreads();
  float v = s[t];
  #pragma unroll
  for(int d=1; d<15; ++d) v = fminf(v, s[t+d]);
  rowm2[(size_t)n*HWSZ + (size_t)y*WW + t] = f2h(v);
}

// -------- hbox4 with fused col-min prologue (reads rowm2) + horizontal box sums + P4 --------
__global__ void k_hbox4(const u16* __restrict__ guidh, const u16* __restrict__ rowm2,
                        uint2* __restrict__ h4, float4* __restrict__ P4){
  __shared__ float4 wsum[8];
  __shared__ float4 pref[WW];
  int b = blockIdx.x; int n = b >> 6; int g = b & 63; int t = threadIdx.x;
  int lane = t & 63, wv = t >> 6;
  // colmin prologue: thread t = column t; rows g*8-7 .. g*8+14 (22), OOB = 1.0
  const u16* rb = rowm2 + (size_t)n*HWSZ;
  float val[22];
  #pragma unroll
  for(int r=0; r<22; ++r){
    int yy = g*8 - 7 + r;
    val[r] = (yy >= 0 && yy < HH) ? h2f(rb[(size_t)yy*WW + t]) : 1.0f;
  }
  float Pv[8];
  #pragma unroll
  for(int j=0; j<8; ++j){
    float mn = val[j];
    #pragma unroll
    for(int d=1; d<15; ++d) mn = fminf(mn, val[j+d]);
    Pv[j] = h2f(f2h(1.0f - 0.95f*mn));   // replicate old f16 round-trip exactly
  }
  float4 psum = {0.f,0.f,0.f,0.f};
  for(int j=0; j<8; ++j){
    int y = g*8 + j;
    size_t off = (size_t)n*HWSZ + (size_t)y*WW + t;
    float I = h2f(guidh[off]);
    float P = Pv[j];
    float4 s; s.x = I; s.y = P; s.z = I*P; s.w = I*I;
    #pragma unroll
    for(int d=1; d<64; d<<=1){
      float ux=__shfl_up(s.x,d), uy=__shfl_up(s.y,d), uz=__shfl_up(s.z,d), uw=__shfl_up(s.w,d);
      if(lane >= d){ s.x+=ux; s.y+=uy; s.z+=uz; s.w+=uw; }
    }
    if(lane == 63) wsum[wv] = s;
    __syncthreads();
    float4 c = {0.f,0.f,0.f,0.f};
    for(int w=0; w<wv; ++w){ float4 q=wsum[w]; c.x+=q.x; c.y+=q.y; c.z+=q.z; c.w+=q.w; }
    s.x+=c.x; s.y+=c.y; s.z+=c.z; s.w+=c.w;
    pref[t] = s;
    __syncthreads();
    int hi = min(t+GR, WW-1);
    float4 S = pref[hi];
    if(t >= GR+1){ float4 L = pref[t-GR-1]; S.x-=L.x; S.y-=L.y; S.z-=L.z; S.w-=L.w; }
    uint2 pk = pack_h4(S);
    h4[off] = pk;
    float4 r = unpack_h4(pk);     // accumulate ROUNDED values
    psum.x+=r.x; psum.y+=r.y; psum.z+=r.z; psum.w+=r.w;
    __syncthreads();
  }
  P4[((size_t)n*64 + g)*WW + t] = psum;
}

// -------- horizontal 81-tap box sums of (a,b); 8 rows/block; emits P2 partial --------
__global__ void k_hbox2(const u32* __restrict__ ab, u32* __restrict__ hab,
                        float2* __restrict__ P2){
  __shared__ float2 wsum[8];
  __shared__ float2 pref[WW];
  int b = blockIdx.x; int n = b >> 6; int g = b & 63; int t = threadIdx.x;
  int lane = t & 63, wv = t >> 6;
  float2 psum = {0.f,0.f};
  for(int j=0; j<8; ++j){
    int y = g*8 + j;
    size_t off = (size_t)n*HWSZ + (size_t)y*WW + t;
    float2 s = unpack_h2(ab[off]);
    #pragma unroll
    for(int d=1; d<64; d<<=1){
      float ux=__shfl_up(s.x,d), uy=__shfl_up(s.y,d);
      if(lane >= d){ s.x+=ux; s.y+=uy; }
    }
    if(lane == 63) wsum[wv] = s;
    __syncthreads();
    float2 c = {0.f,0.f};
    for(int w=0; w<wv; ++w){ float2 q=wsum[w]; c.x+=q.x; c.y+=q.y; }
    s.x+=c.x; s.y+=c.y;
    pref[t] = s;
    __syncthreads();
    int hi = min(t+GR, WW-1);
    float2 S = pref[hi];
    if(t >= GR+1){ float2 L = pref[t-GR-1]; S.x-=L.x; S.y-=L.y; }
    u32 pk = pack_h2(S.x, S.y);
    hab[off] = pk;
    float2 r = unpack_h2(pk);
    psum.x+=r.x; psum.y+=r.y;
    __syncthreads();
  }
  P2[((size_t)n*64 + g)*WW + t] = psum;
}

// ---------------- vertical 81-tap running sums (pyramid init, y-chunk 8) -> a,b ----------------
__global__ void k_vbox_ab(const uint2* __restrict__ h4, const float4* __restrict__ P4,
                          u32* __restrict__ ab){
  int xc = blockIdx.x*256 + threadIdx.x;
  int n = blockIdx.z;
  int y0 = blockIdx.y*8;
  const uint2* hb = h4 + (size_t)n*HWSZ;
  const float4* pb = P4 + (size_t)n*64*WW + xc;
  u32* abb = ab + (size_t)n*HWSZ;
  int nx = min(xc+GR, WW-1) - max(xc-GR, 0) + 1;

  int lo = y0-GR; if(lo < 0) lo = 0;
  int hi = y0+GR; if(hi > HH-1) hi = HH-1;
  int g_lo = lo >> 3;
  int g_hi = ((hi+1) >> 3) - 1;
  float s0=0.f, s1=0.f, s2=0.f, s3=0.f;
  #pragma unroll 6
  for(int g=g_lo; g<=g_hi; ++g){
    float4 v = pb[(size_t)g*WW];
    s0+=v.x; s1+=v.y; s2+=v.z; s3+=v.w;
  }
  for(int y=(g_hi+1)*8; y<=hi; ++y){
    float4 v = unpack_h4(hb[(size_t)y*WW + xc]);
    s0+=v.x; s1+=v.y; s2+=v.z; s3+=v.w;
  }

  #pragma unroll
  for(int g=0; g<2; ++g){
    uint2 ad[4], sb[4];
    bool va4[4], vs4[4];
    #pragma unroll
    for(int j=0; j<4; ++j){
      int y = y0 + g*4 + j;
      int ya = y+GR+1, yr = y-GR;
      va4[j] = (ya < HH); vs4[j] = (yr >= 0);
      ad[j] = va4[j] ? hb[(size_t)ya*WW + xc] : make_uint2(0u,0u);
      sb[j] = vs4[j] ? hb[(size_t)yr*WW + xc] : make_uint2(0u,0u);
    }
    #pragma unroll
    for(int j=0; j<4; ++j){
      int y = y0 + g*4 + j;
      int ny = min(y+GR, HH-1) - max(y-GR, 0) + 1;
      float rc = 1.f/(float)(nx*ny);
      float mI=s0*rc, mP=s1*rc, mIp=s2*rc, mII=s3*rc;
      float va = (mIp - mI*mP) / (mII - mI*mI + 1e-3f);
      float vb = mP - va*mI;
      abb[(size_t)y*WW + xc] = pack_h2(va, vb);
      if(va4[j]){ float4 v = unpack_h4(ad[j]); s0+=v.x; s1+=v.y; s2+=v.z; s3+=v.w; }
      if(vs4[j]){ float4 v = unpack_h4(sb[j]); s0-=v.x; s1-=v.y; s2-=v.z; s3-=v.w; }
    }
  }
}

// ---------------- vertical sums of (a,b) + pyramid -> T -> final composite ----------------
__global__ void k_final(const u32* __restrict__ hab, const float2* __restrict__ P2,
                        const u16* __restrict__ imgh,
                        const float* __restrict__ A, float* __restrict__ out){
  int xc = blockIdx.x*256 + threadIdx.x;
  int n = blockIdx.z;
  int y0 = blockIdx.y*8;
  float A0=A[n*8+0], A1=A[n*8+1], A2=A[n*8+2];
  const u32* hb = hab + (size_t)n*HWSZ;
  const float2* pb = P2 + (size_t)n*64*WW + xc;
  int nx = min(xc+GR, WW-1) - max(xc-GR, 0) + 1;
  const u16* ib = imgh + (size_t)n*3*HWSZ;
  float* ob = out + (size_t)n*3*HWSZ;

  int lo = y0-GR; if(lo < 0) lo = 0;
  int hi = y0+GR; if(hi > HH-1) hi = HH-1;
  int g_lo = lo >> 3;
  int g_hi = ((hi+1) >> 3) - 1;
  float sa=0.f, sb=0.f;
  #pragma unroll 6
  for(int g=g_lo; g<=g_hi; ++g){
    float2 v = pb[(size_t)g*WW];
    sa+=v.x; sb+=v.y;
  }
  for(int y=(g_hi+1)*8; y<=hi; ++y){
    float2 v = unpack_h2(hb[(size_t)y*WW + xc]);
    sa+=v.x; sb+=v.y;
  }

  #pragma unroll
  for(int g=0; g<2; ++g){
    u32 ad[4], su[4];
    bool va4[4], vs4[4];
    #pragma unroll
    for(int j=0; j<4; ++j){
      int y = y0 + g*4 + j;
      int ya = y+GR+1, yr = y-GR;
      va4[j] = (ya < HH); vs4[j] = (yr >= 0);
      ad[j] = va4[j] ? hb[(size_t)ya*WW + xc] : 0u;
      su[j] = vs4[j] ? hb[(size_t)yr*WW + xc] : 0u;
    }
    #pragma unroll
    for(int j=0; j<4; ++j){
      int y = y0 + g*4 + j;
      int ny = min(y+GR, HH-1) - max(y-GR, 0) + 1;
      float rc = 1.f/(float)(nx*ny);
      size_t oy = (size_t)y*WW + xc;
      float i0 = h2f(ib[oy]), i1 = h2f(ib[oy+HWSZ]), i2 = h2f(ib[oy+2*HWSZ]);
      float g2 = (0.2989f*(2.f*i0-1.f) + 0.587f*(2.f*i1-1.f) + 0.114f*(2.f*i2-1.f) + 1.f)*0.5f;
      float T = (sa*g2 + sb)*rc;
      float rT = 1.0f / T;
      __builtin_nontemporal_store((i0-A0)*rT + A0, &ob[oy]);
      __builtin_nontemporal_store((i1-A1)*rT + A1, &ob[oy+HWSZ]);
      __builtin_nontemporal_store((i2-A2)*rT + A2, &ob[oy+2*HWSZ]);
      if(va4[j]){ float2 v = unpack_h2(ad[j]); sa+=v.x; sb+=v.y; }
      if(vs4[j]){ float2 v = unpack_h2(su[j]); sa-=v.x; sb-=v.y; }
    }
  }
}

extern "C" void kernel_launch(void* const* d_in, const int* in_sizes, int n_in,
                              void* d_out, int out_size, void* d_ws, size_t ws_size,
                              hipStream_t stream) {
  const float* x = (const float*)d_in[0];
  float* out = (float*)d_out;
  char* ws = (char*)d_ws;
  const size_t MB = 1u<<20;

  // region map (80.6 MiB total):
  u16*   imgh  = (u16*)(ws + 0);            // 24 MiB, live whole pass
  u16*   guidh = (u16*)(ws + 24*MB);        //  8 MiB, prep -> hbox4
  // region A (32 MiB):
  float* rowm  = (float*)(ws + 32*MB);      // 16 MiB, prep -> colmin_dark
  float* dark  = (float*)(ws + 48*MB);      // 16 MiB, colmin_dark -> sel4
  uint2* h4    = (uint2*)(ws + 32*MB);      // 32 MiB, hbox4 -> vbox   (over rowm+dark)
  u32*   hab   = (u32*)(ws + 32*MB);        // 16 MiB, hbox2 -> final  (over h4)
  // region B (16 MiB):
  u16*   rowm2 = (u16*)(ws + 64*MB);        //  8 MiB, rowmin2 -> hbox4 (live!)
  float4* P4   = (float4*)(ws + 72*MB);     //  8 MiB, hbox4 -> vbox
  float2* P2   = (float2*)(ws + 64*MB);     //  4 MiB, hbox2 -> final (over rowm2, dead after hbox4)
  // ab scratch lives in d_out (overwritten by k_final, which doesn't read it)
  u32*   ab    = (u32*)out;                 // 16 MiB
  // selection state
  char* sm = ws + 80*MB;
  u32* hist1 = (u32*)sm;                       // 512 KiB (reused as ties)
  u32* ties  = hist1;
  u32* hist2 = (u32*)(sm + 524288);            // 64 KiB
  u32* st    = (u32*)(sm + 524288 + 65536);    // 1 KiB
  float* sums= (float*)(sm + 524288 + 65536 + 1024);
  float* Abuf= (float*)(sm + 524288 + 65536 + 1024 + 512);
  int zwords = (524288 + 65536 + 1024 + 512) / 4;

  // 1. prep: img16 + guid16 + row-min (f32, exact) + state zero
  k_prep<<<dim3(NIMG*HH), dim3(512), 0, stream>>>(x, imgh, guidh, rowm, (u32*)sm, zwords);
  // 2. col-min dark + fused hist1
  k_colmin_dark<<<dim3(HH, NIMG), dim3(128), 0, stream>>>(rowm, dark, hist1);
  // 3. atmospheric light: hist2(+csel1), sel4(+csel2), sel5
  k_hist2<<<dim3(NIMG, 8), dim3(1024), 0, stream>>>(dark, hist1, hist2, st);
  k_sel4<<<dim3(NIMG, 8), dim3(1024), 0, stream>>>(dark, x, hist2, st, sums, ties);
  k_sel5<<<dim3(NIMG), dim3(1024), 0, stream>>>(x, st, sums, ties, Abuf);
  // 4. transmission raw (row-min only; col-min fused into hbox4)
  k_rowmin2<<<dim3(NIMG*HH), dim3(512), 0, stream>>>(imgh, Abuf, rowm2);
  // 5. guided filter round 1 (colmin_pT fused into hbox4 prologue)
  k_hbox4<<<dim3(NIMG*64), dim3(512), 0, stream>>>(guidh, rowm2, h4, P4);
  k_vbox_ab<<<dim3(2, HH/8, NIMG), dim3(256), 0, stream>>>(h4, P4, ab);
  // 6. guided filter round 2 -> T -> final output
  k_hbox2<<<dim3(NIMG*64), dim3(512), 0, stream>>>(ab, hab, P2);
  k_final<<<dim3(2, HH/8, NIMG), dim3(256), 0, stream>>>(hab, P2, imgh, Abuf, out);
}

// Round 12
// 208.919 us; speedup vs baseline: 1.1967x; 1.1967x over previous
//
#include <hip/hip_runtime.h>
#include <hip/hip_fp16.h>

typedef unsigned int u32;
typedef unsigned short u16;

#define NIMG 16
#define HH 512
#define WW 512
#define HWSZ (HH*WW)
#define TOPN 2621u
#define TIE_CAP 8192
#define GR 40

// ---------- f16 packing helpers ----------
static __device__ inline u16 f2h(float v){ __half h=__float2half_rn(v); return *reinterpret_cast<u16*>(&h); }
static __device__ inline float h2f(u16 v){ __half h=*reinterpret_cast<__half*>(&v); return __half2float(h); }
static __device__ inline uint2 pack_h4(float4 S){
  __half2 lo = __floats2half2_rn(S.x, S.y);
  __half2 hi = __floats2half2_rn(S.z, S.w);
  uint2 r;
  r.x = *reinterpret_cast<unsigned int*>(&lo);
  r.y = *reinterpret_cast<unsigned int*>(&hi);
  return r;
}
static __device__ inline float4 unpack_h4(uint2 v){
  __half2 lo = *reinterpret_cast<__half2*>(&v.x);
  __half2 hi = *reinterpret_cast<__half2*>(&v.y);
  float2 A = __half22float2(lo), B = __half22float2(hi);
  return make_float4(A.x, A.y, B.x, B.y);
}
static __device__ inline u32 pack_h2(float a, float b){
  __half2 h = __floats2half2_rn(a, b);
  return *reinterpret_cast<unsigned int*>(&h);
}
static __device__ inline float2 unpack_h2(u32 v){
  __half2 h = *reinterpret_cast<__half2*>(&v);
  return __half22float2(h);
}

// ---------------- prep: x -> img16(3 planes), guid16, row-min f32 (dark path), zero state ----------------
__global__ void k_prep(const float* __restrict__ x, u16* __restrict__ imgh,
                       u16* __restrict__ guidh, float* __restrict__ rowm,
                       u32* __restrict__ state, int zwords){
  __shared__ float s[WW+14];
  int row = blockIdx.x; int n = row>>9; int y = row&511; int t = threadIdx.x;
  int zi = row*512 + t;
  if(zi < zwords) state[zi] = 0;
  const float* xb = x + (size_t)n*3*HWSZ + (size_t)y*WW + t;
  float x0=xb[0], x1=xb[HWSZ], x2=xb[2*HWSZ];
  float i0=(x0+1.f)*0.5f, i1=(x1+1.f)*0.5f, i2=(x2+1.f)*0.5f;
  size_t po = (size_t)n*3*HWSZ + (size_t)y*WW + t;
  imgh[po] = f2h(i0); imgh[po+HWSZ] = f2h(i1); imgh[po+2*HWSZ] = f2h(i2);
  float g = (0.2989f*x0 + 0.587f*x1 + 0.114f*x2 + 1.f)*0.5f;   // exact reference form
  size_t qo = (size_t)n*HWSZ + (size_t)y*WW + t;
  guidh[qo] = f2h(g);
  float m = fminf(i0, fminf(i1, i2));
  s[t+7] = m;
  if(t < 7) s[t] = 1.0f;
  if(t >= WW-7) s[t+14] = 1.0f;
  __syncthreads();
  float v = s[t];
  #pragma unroll
  for(int d=1; d<15; ++d) v = fminf(v, s[t+d]);
  rowm[qo] = v;
}

// ---------------- 15-tap col min f32 (dark) ----------------
__global__ void k_colmin_dark(const float* __restrict__ in, float* __restrict__ out){
  int x4 = threadIdx.x;            // 128 threads = 512 floats
  int y = blockIdx.x;
  int n = blockIdx.y;
  const float4* base = (const float4*)(in + (size_t)n*HWSZ);
  float4 v = {3.0e38f,3.0e38f,3.0e38f,3.0e38f};
  #pragma unroll
  for(int d=-7; d<=7; ++d){
    int yy = y + d;
    if(yy >= 0 && yy < HH){
      float4 tp = base[(size_t)yy*(WW/4) + x4];
      v.x=fminf(v.x,tp.x); v.y=fminf(v.y,tp.y); v.z=fminf(v.z,tp.z); v.w=fminf(v.w,tp.w);
    } else {
      v.x=fminf(v.x,1.f); v.y=fminf(v.y,1.f); v.z=fminf(v.z,1.f); v.w=fminf(v.w,1.f);
    }
  }
  ((float4*)(out + (size_t)n*HWSZ))[(size_t)y*(WW/4) + x4] = v;
}

__device__ inline u32 block_scan_incl(u32 v, int t, u32* wsum){
  #pragma unroll
  for(int d=1; d<64; d<<=1){
    u32 u = __shfl_up(v, d);
    if((t & 63) >= d) v += u;
  }
  if((t & 63) == 63) wsum[t >> 6] = v;
  __syncthreads();
  u32 carry = 0;
  for(int w=0; w < (t >> 6); ++w) carry += wsum[w];
  return v + carry;
}

// ---------------- selection: histogram bits [22:10] ----------------
__global__ void k_hist1(const float* __restrict__ dark, u32* __restrict__ hist1){
  __shared__ u32 h[8192];
  int n = blockIdx.x, part = blockIdx.y, t = threadIdx.x;  // 1024 threads
  for(int i=t; i<8192; i+=1024) h[i] = 0;
  __syncthreads();
  const u32* d = (const u32*)(dark + (size_t)n*HWSZ);
  int per = HWSZ/8, i0 = part*per;
  for(int i=i0+t; i<i0+per; i+=1024){
    u32 key = d[i];
    int b = (int)(key >> 10) - 0xFC000;
    b = max(0, min(8191, b));
    atomicAdd(&h[b], 1u);
  }
  __syncthreads();
  u32* gh = hist1 + n*8192;
  for(int i=t; i<8192; i+=1024) if(h[i]) atomicAdd(&gh[i], h[i]);
}

// ---------------- hist2 with redundant csel1 prologue (plain loads, no fences) ----------------
__global__ void k_hist2(const float* __restrict__ dark, const u32* __restrict__ hist1,
                        u32* __restrict__ hist2, u32* __restrict__ st){
  __shared__ u32 h[1024];
  __shared__ u32 wsum[16];
  __shared__ u32 bc[2];
  int n = blockIdx.x, part = blockIdx.y, t = threadIdx.x;   // 1024 threads
  h[t] = 0;
  // csel1 prologue: every block redundantly scans hist1 (built in a prior dispatch)
  const u32* hh = hist1 + n*8192;
  u32 loc[8]; u32 ps = 0;
  #pragma unroll
  for(int k=0; k<8; ++k){
    loc[k] = hh[8191 - (t*8 + k)];
    ps += loc[k];
  }
  u32 incl = block_scan_incl(ps, t, wsum);
  u32 excl = incl - ps;
  if(excl < TOPN && incl >= TOPN){
    u32 cum = excl;
    #pragma unroll
    for(int k=0; k<8; ++k){
      if(cum + loc[k] >= TOPN){
        bc[0] = (u32)(8191 - (t*8+k));
        bc[1] = cum;
        st[n*16+0] = bc[0];          // racing identical writes across blocks: benign
        st[n*16+1] = cum;
        break;
      }
      cum += loc[k];
    }
  }
  __syncthreads();
  int bin_hi = (int)bc[0];
  const u32* d = (const u32*)(dark + (size_t)n*HWSZ);
  int per = HWSZ/8, i0 = part*per;
  for(int i=i0+t; i<i0+per; i+=1024){
    u32 key = d[i];
    if(((int)(key >> 10) - 0xFC000) == bin_hi) atomicAdd(&h[key & 1023u], 1u);
  }
  __syncthreads();
  if(h[t]) atomicAdd(&hist2[n*1024 + t], h[t]);
}

// ---------------- sel4 with redundant csel2 prologue; sums over dark > v*, gather ties ----------------
__global__ void k_sel4(const float* __restrict__ dark, const float* __restrict__ x,
                       const u32* __restrict__ hist2, u32* __restrict__ st,
                       float* __restrict__ sums, u32* __restrict__ ties){
  __shared__ u32 wsum[16];
  __shared__ u32 bc[1];
  __shared__ float red[1024];
  int n = blockIdx.x, part = blockIdx.y, t = threadIdx.x;
  // csel2 prologue: every block redundantly scans hist2
  u32 bin_hi    = st[n*16+0];
  u32 cnt_above = st[n*16+1];
  u32 cnt = hist2[n*1024 + (1023 - t)];
  u32 incl = block_scan_incl(cnt, t, wsum);
  u32 excl = incl - cnt;
  u32 need = TOPN - cnt_above;
  if(excl < need && incl >= need){
    u32 lo = (u32)(1023 - t);
    u32 cnt_gt = cnt_above + excl;
    bc[0] = ((bin_hi + 0xFC000u) << 10) | lo;
    st[n*16+6] = TOPN - cnt_gt;     // k_need for sel5 (racing identical writes: benign)
  }
  __syncthreads();
  u32 vb = bc[0];
  const u32* d = (const u32*)(dark + (size_t)n*HWSZ);
  const float* xb = x + (size_t)n*3*HWSZ;
  float a0=0.f, a1=0.f, a2=0.f;
  int per = HWSZ/8, i0 = part*per;
  for(int i=i0+t; i<i0+per; i+=1024){
    u32 key = d[i];
    if(key > vb){
      a0 += xb[i]; a1 += xb[i+HWSZ]; a2 += xb[i+2*HWSZ];
    } else if(key == vb){
      u32 pos = atomicAdd(&st[n*16+7], 1u);
      if(pos < TIE_CAP) ties[n*TIE_CAP + pos] = (u32)i;
    }
  }
  red[t]=a0; __syncthreads();
  for(int s=512;s>0;s>>=1){ if(t<s) red[t]+=red[t+s]; __syncthreads(); }
  if(t==0) atomicAdd(&sums[n*8+0], red[0]);
  __syncthreads();
  red[t]=a1; __syncthreads();
  for(int s=512;s>0;s>>=1){ if(t<s) red[t]+=red[t+s]; __syncthreads(); }
  if(t==0) atomicAdd(&sums[n*8+1], red[0]);
  __syncthreads();
  red[t]=a2; __syncthreads();
  for(int s=512;s>0;s>>=1){ if(t<s) red[t]+=red[t+s]; __syncthreads(); }
  if(t==0) atomicAdd(&sums[n*8+2], red[0]);
}

// ---------------- sel5: exact top_k tie-break by smallest index (binary search cutoff) ----------------
__global__ void k_sel5(const float* __restrict__ x, const u32* __restrict__ st,
                       const float* __restrict__ sums, const u32* __restrict__ ties,
                       float* __restrict__ A){
  __shared__ u32 tl[TIE_CAP];
  __shared__ u32 redu[1024];
  __shared__ float red[1024];
  __shared__ float fin[3];
  int n = blockIdx.x, t = threadIdx.x;   // 1024
  u32 k_need = st[n*16+6];
  u32 m = st[n*16+7]; if(m > TIE_CAP) m = TIE_CAP;
  const float* xb = x + (size_t)n*3*HWSZ;
  const u32* tb = ties + n*TIE_CAP;
  for(u32 e=t; e<m; e+=1024) tl[e] = tb[e];
  __syncthreads();
  u32 lo = 0, hi = HWSZ;
  while(lo < hi){
    u32 mid = (lo + hi) >> 1;
    u32 c = 0;
    for(u32 e=t; e<m; e+=1024) c += (tl[e] < mid) ? 1u : 0u;
    redu[t] = c; __syncthreads();
    for(int s=512;s>0;s>>=1){ if(t<s) redu[t]+=redu[t+s]; __syncthreads(); }
    u32 total = redu[0]; __syncthreads();
    if(total >= k_need) hi = mid; else lo = mid + 1;
  }
  u32 C = lo;
  float a0=0.f, a1=0.f, a2=0.f;
  for(u32 e=t; e<m; e+=1024){
    u32 idx = tl[e];
    if(idx < C){ a0 += xb[idx]; a1 += xb[idx+HWSZ]; a2 += xb[idx+2*HWSZ]; }
  }
  red[t]=a0; __syncthreads();
  for(int s=512;s>0;s>>=1){ if(t<s) red[t]+=red[t+s]; __syncthreads(); }
  if(t==0) fin[0]=red[0];
  __syncthreads();
  red[t]=a1; __syncthreads();
  for(int s=512;s>0;s>>=1){ if(t<s) red[t]+=red[t+s]; __syncthreads(); }
  if(t==0) fin[1]=red[0];
  __syncthreads();
  red[t]=a2; __syncthreads();
  for(int s=512;s>0;s>>=1){ if(t<s) red[t]+=red[t+s]; __syncthreads(); }
  if(t==0){
    fin[2]=red[0];
    for(int c=0;c<3;++c){
      float tot = sums[n*8+c] + fin[c];
      float Ac = (tot / 2621.0f + 1.0f) * 0.5f;
      A[n*8+c]   = Ac;
      A[n*8+4+c] = 1.0f / Ac;
    }
  }
}

// ---------------- rowmin of img/A (f16 img in, f16 out) ----------------
__global__ void k_rowmin2(const u16* __restrict__ imgh, const float* __restrict__ A,
                          u16* __restrict__ rowm2){
  __shared__ float s[WW+14];
  int row = blockIdx.x; int n = row>>9; int y = row&511; int t = threadIdx.x;
  float ia0=A[n*8+4], ia1=A[n*8+5], ia2=A[n*8+6];
  size_t po = (size_t)n*3*HWSZ + (size_t)y*WW + t;
  float i0=h2f(imgh[po]), i1=h2f(imgh[po+HWSZ]), i2=h2f(imgh[po+2*HWSZ]);
  float m = fminf(i0*ia0, fminf(i1*ia1, i2*ia2));
  s[t+7] = m;
  if(t < 7) s[t] = 1.0f;
  if(t >= WW-7) s[t+14] = 1.0f;
  __syncthreads();
  float v = s[t];
  #pragma unroll
  for(int d=1; d<15; ++d) v = fminf(v, s[t+d]);
  rowm2[(size_t)n*HWSZ + (size_t)y*WW + t] = f2h(v);
}

// -------- hbox4 with fused col-min prologue (reads rowm2) + horizontal box sums + P4 --------
__global__ void k_hbox4(const u16* __restrict__ guidh, const u16* __restrict__ rowm2,
                        uint2* __restrict__ h4, float4* __restrict__ P4){
  __shared__ float4 wsum[8];
  __shared__ float4 pref[WW];
  int b = blockIdx.x; int n = b >> 6; int g = b & 63; int t = threadIdx.x;
  int lane = t & 63, wv = t >> 6;
  // colmin prologue: thread t = column t; rows g*8-7 .. g*8+14 (22), OOB = 1.0
  const u16* rb = rowm2 + (size_t)n*HWSZ;
  float val[22];
  #pragma unroll
  for(int r=0; r<22; ++r){
    int yy = g*8 - 7 + r;
    val[r] = (yy >= 0 && yy < HH) ? h2f(rb[(size_t)yy*WW + t]) : 1.0f;
  }
  float Pv[8];
  #pragma unroll
  for(int j=0; j<8; ++j){
    float mn = val[j];
    #pragma unroll
    for(int d=1; d<15; ++d) mn = fminf(mn, val[j+d]);
    Pv[j] = h2f(f2h(1.0f - 0.95f*mn));   // replicate old f16 round-trip exactly
  }
  float4 psum = {0.f,0.f,0.f,0.f};
  for(int j=0; j<8; ++j){
    int y = g*8 + j;
    size_t off = (size_t)n*HWSZ + (size_t)y*WW + t;
    float I = h2f(guidh[off]);
    float P = Pv[j];
    float4 s; s.x = I; s.y = P; s.z = I*P; s.w = I*I;
    #pragma unroll
    for(int d=1; d<64; d<<=1){
      float ux=__shfl_up(s.x,d), uy=__shfl_up(s.y,d), uz=__shfl_up(s.z,d), uw=__shfl_up(s.w,d);
      if(lane >= d){ s.x+=ux; s.y+=uy; s.z+=uz; s.w+=uw; }
    }
    if(lane == 63) wsum[wv] = s;
    __syncthreads();
    float4 c = {0.f,0.f,0.f,0.f};
    for(int w=0; w<wv; ++w){ float4 q=wsum[w]; c.x+=q.x; c.y+=q.y; c.z+=q.z; c.w+=q.w; }
    s.x+=c.x; s.y+=c.y; s.z+=c.z; s.w+=c.w;
    pref[t] = s;
    __syncthreads();
    int hi = min(t+GR, WW-1);
    float4 S = pref[hi];
    if(t >= GR+1){ float4 L = pref[t-GR-1]; S.x-=L.x; S.y-=L.y; S.z-=L.z; S.w-=L.w; }
    uint2 pk = pack_h4(S);
    h4[off] = pk;
    float4 r = unpack_h4(pk);     // accumulate ROUNDED values
    psum.x+=r.x; psum.y+=r.y; psum.z+=r.z; psum.w+=r.w;
    __syncthreads();
  }
  P4[((size_t)n*64 + g)*WW + t] = psum;
}

// -------- horizontal 81-tap box sums of (a,b); 8 rows/block; emits P2 partial --------
__global__ void k_hbox2(const u32* __restrict__ ab, u32* __restrict__ hab,
                        float2* __restrict__ P2){
  __shared__ float2 wsum[8];
  __shared__ float2 pref[WW];
  int b = blockIdx.x; int n = b >> 6; int g = b & 63; int t = threadIdx.x;
  int lane = t & 63, wv = t >> 6;
  float2 psum = {0.f,0.f};
  for(int j=0; j<8; ++j){
    int y = g*8 + j;
    size_t off = (size_t)n*HWSZ + (size_t)y*WW + t;
    float2 s = unpack_h2(ab[off]);
    #pragma unroll
    for(int d=1; d<64; d<<=1){
      float ux=__shfl_up(s.x,d), uy=__shfl_up(s.y,d);
      if(lane >= d){ s.x+=ux; s.y+=uy; }
    }
    if(lane == 63) wsum[wv] = s;
    __syncthreads();
    float2 c = {0.f,0.f};
    for(int w=0; w<wv; ++w){ float2 q=wsum[w]; c.x+=q.x; c.y+=q.y; }
    s.x+=c.x; s.y+=c.y;
    pref[t] = s;
    __syncthreads();
    int hi = min(t+GR, WW-1);
    float2 S = pref[hi];
    if(t >= GR+1){ float2 L = pref[t-GR-1]; S.x-=L.x; S.y-=L.y; }
    u32 pk = pack_h2(S.x, S.y);
    hab[off] = pk;
    float2 r = unpack_h2(pk);
    psum.x+=r.x; psum.y+=r.y;
    __syncthreads();
  }
  P2[((size_t)n*64 + g)*WW + t] = psum;
}

// ---------------- vertical 81-tap running sums (pyramid init, y-chunk 8) -> a,b ----------------
__global__ void k_vbox_ab(const uint2* __restrict__ h4, const float4* __restrict__ P4,
                          u32* __restrict__ ab){
  int xc = blockIdx.x*256 + threadIdx.x;
  int n = blockIdx.z;
  int y0 = blockIdx.y*8;
  const uint2* hb = h4 + (size_t)n*HWSZ;
  const float4* pb = P4 + (size_t)n*64*WW + xc;
  u32* abb = ab + (size_t)n*HWSZ;
  int nx = min(xc+GR, WW-1) - max(xc-GR, 0) + 1;

  int lo = y0-GR; if(lo < 0) lo = 0;
  int hi = y0+GR; if(hi > HH-1) hi = HH-1;
  int g_lo = lo >> 3;
  int g_hi = ((hi+1) >> 3) - 1;
  float s0=0.f, s1=0.f, s2=0.f, s3=0.f;
  #pragma unroll 6
  for(int g=g_lo; g<=g_hi; ++g){
    float4 v = pb[(size_t)g*WW];
    s0+=v.x; s1+=v.y; s2+=v.z; s3+=v.w;
  }
  for(int y=(g_hi+1)*8; y<=hi; ++y){
    float4 v = unpack_h4(hb[(size_t)y*WW + xc]);
    s0+=v.x; s1+=v.y; s2+=v.z; s3+=v.w;
  }

  #pragma unroll
  for(int g=0; g<2; ++g){
    uint2 ad[4], sb[4];
    bool va4[4], vs4[4];
    #pragma unroll
    for(int j=0; j<4; ++j){
      int y = y0 + g*4 + j;
      int ya = y+GR+1, yr = y-GR;
      va4[j] = (ya < HH); vs4[j] = (yr >= 0);
      ad[j] = va4[j] ? hb[(size_t)ya*WW + xc] : make_uint2(0u,0u);
      sb[j] = vs4[j] ? hb[(size_t)yr*WW + xc] : make_uint2(0u,0u);
    }
    #pragma unroll
    for(int j=0; j<4; ++j){
      int y = y0 + g*4 + j;
      int ny = min(y+GR, HH-1) - max(y-GR, 0) + 1;
      float rc = 1.f/(float)(nx*ny);
      float mI=s0*rc, mP=s1*rc, mIp=s2*rc, mII=s3*rc;
      float va = (mIp - mI*mP) / (mII - mI*mI + 1e-3f);
      float vb = mP - va*mI;
      abb[(size_t)y*WW + xc] = pack_h2(va, vb);
      if(va4[j]){ float4 v = unpack_h4(ad[j]); s0+=v.x; s1+=v.y; s2+=v.z; s3+=v.w; }
      if(vs4[j]){ float4 v = unpack_h4(sb[j]); s0-=v.x; s1-=v.y; s2-=v.z; s3-=v.w; }
    }
  }
}

// ---------------- vertical sums of (a,b) + pyramid -> T -> final composite ----------------
__global__ void k_final(const u32* __restrict__ hab, const float2* __restrict__ P2,
                        const u16* __restrict__ imgh,
                        const float* __restrict__ A, float* __restrict__ out){
  int xc = blockIdx.x*256 + threadIdx.x;
  int n = blockIdx.z;
  int y0 = blockIdx.y*8;
  float A0=A[n*8+0], A1=A[n*8+1], A2=A[n*8+2];
  const u32* hb = hab + (size_t)n*HWSZ;
  const float2* pb = P2 + (size_t)n*64*WW + xc;
  int nx = min(xc+GR, WW-1) - max(xc-GR, 0) + 1;
  const u16* ib = imgh + (size_t)n*3*HWSZ;
  float* ob = out + (size_t)n*3*HWSZ;

  int lo = y0-GR; if(lo < 0) lo = 0;
  int hi = y0+GR; if(hi > HH-1) hi = HH-1;
  int g_lo = lo >> 3;
  int g_hi = ((hi+1) >> 3) - 1;
  float sa=0.f, sb=0.f;
  #pragma unroll 6
  for(int g=g_lo; g<=g_hi; ++g){
    float2 v = pb[(size_t)g*WW];
    sa+=v.x; sb+=v.y;
  }
  for(int y=(g_hi+1)*8; y<=hi; ++y){
    float2 v = unpack_h2(hb[(size_t)y*WW + xc]);
    sa+=v.x; sb+=v.y;
  }

  #pragma unroll
  for(int g=0; g<2; ++g){
    u32 ad[4], su[4];
    bool va4[4], vs4[4];
    #pragma unroll
    for(int j=0; j<4; ++j){
      int y = y0 + g*4 + j;
      int ya = y+GR+1, yr = y-GR;
      va4[j] = (ya < HH); vs4[j] = (yr >= 0);
      ad[j] = va4[j] ? hb[(size_t)ya*WW + xc] : 0u;
      su[j] = vs4[j] ? hb[(size_t)yr*WW + xc] : 0u;
    }
    #pragma unroll
    for(int j=0; j<4; ++j){
      int y = y0 + g*4 + j;
      int ny = min(y+GR, HH-1) - max(y-GR, 0) + 1;
      float rc = 1.f/(float)(nx*ny);
      size_t oy = (size_t)y*WW + xc;
      float i0 = h2f(ib[oy]), i1 = h2f(ib[oy+HWSZ]), i2 = h2f(ib[oy+2*HWSZ]);
      float g2 = (0.2989f*(2.f*i0-1.f) + 0.587f*(2.f*i1-1.f) + 0.114f*(2.f*i2-1.f) + 1.f)*0.5f;
      float T = (sa*g2 + sb)*rc;
      float rT = 1.0f / T;
      __builtin_nontemporal_store((i0-A0)*rT + A0, &ob[oy]);
      __builtin_nontemporal_store((i1-A1)*rT + A1, &ob[oy+HWSZ]);
      __builtin_nontemporal_store((i2-A2)*rT + A2, &ob[oy+2*HWSZ]);
      if(va4[j]){ float2 v = unpack_h2(ad[j]); sa+=v.x; sb+=v.y; }
      if(vs4[j]){ float2 v = unpack_h2(su[j]); sa-=v.x; sb-=v.y; }
    }
  }
}

extern "C" void kernel_launch(void* const* d_in, const int* in_sizes, int n_in,
                              void* d_out, int out_size, void* d_ws, size_t ws_size,
                              hipStream_t stream) {
  const float* x = (const float*)d_in[0];
  float* out = (float*)d_out;
  char* ws = (char*)d_ws;
  const size_t MB = 1u<<20;

  // region map (80.6 MiB total):
  u16*   imgh  = (u16*)(ws + 0);            // 24 MiB, live whole pass
  u16*   guidh = (u16*)(ws + 24*MB);        //  8 MiB, prep -> hbox4
  // region A (32 MiB):
  float* rowm  = (float*)(ws + 32*MB);      // 16 MiB, prep -> colmin_dark
  float* dark  = (float*)(ws + 48*MB);      // 16 MiB, colmin_dark -> sel4
  uint2* h4    = (uint2*)(ws + 32*MB);      // 32 MiB, hbox4 -> vbox   (over rowm+dark)
  u32*   hab   = (u32*)(ws + 32*MB);        // 16 MiB, hbox2 -> final  (over h4)
  // region B (16 MiB):
  u16*   rowm2 = (u16*)(ws + 64*MB);        //  8 MiB, rowmin2 -> hbox4 (live!)
  float4* P4   = (float4*)(ws + 72*MB);     //  8 MiB, hbox4 -> vbox
  float2* P2   = (float2*)(ws + 64*MB);     //  4 MiB, hbox2 -> final (over rowm2, dead after hbox4)
  // ab scratch lives in d_out (overwritten by k_final, which doesn't read it)
  u32*   ab    = (u32*)out;                 // 16 MiB
  // selection state
  char* sm = ws + 80*MB;
  u32* hist1 = (u32*)sm;                       // 512 KiB (reused as ties)
  u32* ties  = hist1;
  u32* hist2 = (u32*)(sm + 524288);            // 64 KiB
  u32* st    = (u32*)(sm + 524288 + 65536);    // 1 KiB
  float* sums= (float*)(sm + 524288 + 65536 + 1024);
  float* Abuf= (float*)(sm + 524288 + 65536 + 1024 + 512);
  int zwords = (524288 + 65536 + 1024 + 512) / 4;

  // 1. prep: img16 + guid16 + row-min (f32, exact) + state zero
  k_prep<<<dim3(NIMG*HH), dim3(512), 0, stream>>>(x, imgh, guidh, rowm, (u32*)sm, zwords);
  // 2. col-min dark (plain, fast)
  k_colmin_dark<<<dim3(HH, NIMG), dim3(128), 0, stream>>>(rowm, dark);
  // 3. atmospheric light: hist1, hist2(+csel1), sel4(+csel2), sel5
  k_hist1<<<dim3(NIMG, 8), dim3(1024), 0, stream>>>(dark, hist1);
  k_hist2<<<dim3(NIMG, 8), dim3(1024), 0, stream>>>(dark, hist1, hist2, st);
  k_sel4<<<dim3(NIMG, 8), dim3(1024), 0, stream>>>(dark, x, hist2, st, sums, ties);
  k_sel5<<<dim3(NIMG), dim3(1024), 0, stream>>>(x, st, sums, ties, Abuf);
  // 4. transmission raw (row-min only; col-min fused into hbox4)
  k_rowmin2<<<dim3(NIMG*HH), dim3(512), 0, stream>>>(imgh, Abuf, rowm2);
  // 5. guided filter round 1 (colmin_pT fused into hbox4 prologue)
  k_hbox4<<<dim3(NIMG*64), dim3(512), 0, stream>>>(guidh, rowm2, h4, P4);
  k_vbox_ab<<<dim3(2, HH/8, NIMG), dim3(256), 0, stream>>>(h4, P4, ab);
  // 6. guided filter round 2 -> T -> final output
  k_hbox2<<<dim3(NIMG*64), dim3(512), 0, stream>>>(ab, hab, P2);
  k_final<<<dim3(2, HH/8, NIMG), dim3(256), 0, stream>>>(hab, P2, imgh, Abuf, out);
}